// Round 1
// baseline (532.088 us; speedup 1.0000x reference)
//
#include <hip/hip_runtime.h>
#include <stdint.h>
#include <stddef.h>

#define D_MODEL 1024
#define D_STATE 16
#define D_INNER 2048
#define BATCH   2
#define SEQ     1024
#define MROWS   (BATCH*SEQ)   // 2048

typedef __bf16 bf16x8 __attribute__((ext_vector_type(8)));
typedef float  f32x4  __attribute__((ext_vector_type(4)));

__device__ __forceinline__ unsigned short f2bf(float f) {
    unsigned int u = __float_as_uint(f);
    u += 0x7fffu + ((u >> 16) & 1u);      // RNE
    return (unsigned short)(u >> 16);
}

// ---------------- fp32 -> bf16 conversion (x, in_proj_w, out_w) ----------------
__global__ void cvt_bf16_kernel(const float* __restrict__ src,
                                unsigned short* __restrict__ dst, int n) {
    int i = (blockIdx.x * blockDim.x + threadIdx.x) * 4;
    if (i < n) {
        float4 v = *(const float4*)(src + i);
        ushort4 o;
        o.x = f2bf(v.x); o.y = f2bf(v.y); o.z = f2bf(v.z); o.w = f2bf(v.w);
        *(ushort4*)(dst + i) = o;
    }
}

// ---------------- bf16 MFMA GEMM: C[m,n] = sum_k A[m,k]*Bw[n,k] (+bias[n]) -----
// A: M x K bf16 row-major, Bw: N x K bf16 row-major, C: M x N fp32.
// 128x128 block tile, BK=32, 256 threads (4 waves, 2x2, each 64x64).
template<bool BIAS>
__global__ void gemm_bf16_kernel(const unsigned short* __restrict__ A,
                                 const unsigned short* __restrict__ Bw,
                                 float* __restrict__ C,
                                 const float* __restrict__ bias,
                                 int M, int N, int K) {
    // padded row stride 40 bf16 (80B = odd multiple of 16B -> 2-way on b128 reads)
    __shared__ __align__(16) unsigned short Al[128 * 40];
    __shared__ __align__(16) unsigned short Bl[128 * 40];

    const int tid  = threadIdx.x;
    const int lane = tid & 63;
    const int wid  = tid >> 6;
    const int wm   = wid >> 1;        // 0..1
    const int wn   = wid & 1;         // 0..1
    const int ln   = lane & 15;
    const int q    = lane >> 4;       // 0..3
    const int mblk = blockIdx.y * 128;
    const int nblk = blockIdx.x * 128;

    f32x4 acc[4][4] = {};

    for (int k0 = 0; k0 < K; k0 += 32) {
        // stage: 512 chunks of 8 bf16 (16B); each thread does 2 per tile
        #pragma unroll
        for (int h = 0; h < 2; ++h) {
            int c    = tid + h * 256;
            int row  = c >> 2;
            int part = c & 3;
            uint4 va = *(const uint4*)(A  + (size_t)(mblk + row) * K + k0 + part * 8);
            *(uint4*)(Al + row * 40 + part * 8) = va;
            uint4 vb = *(const uint4*)(Bw + (size_t)(nblk + row) * K + k0 + part * 8);
            *(uint4*)(Bl + row * 40 + part * 8) = vb;
        }
        __syncthreads();

        bf16x8 af[4], bfr[4];
        #pragma unroll
        for (int mt = 0; mt < 4; ++mt)
            af[mt] = *(const bf16x8*)(Al + (wm * 64 + mt * 16 + ln) * 40 + q * 8);
        #pragma unroll
        for (int nt = 0; nt < 4; ++nt)
            bfr[nt] = *(const bf16x8*)(Bl + (wn * 64 + nt * 16 + ln) * 40 + q * 8);

        #pragma unroll
        for (int mt = 0; mt < 4; ++mt)
            #pragma unroll
            for (int nt = 0; nt < 4; ++nt)
                acc[mt][nt] = __builtin_amdgcn_mfma_f32_16x16x32_bf16(
                    af[mt], bfr[nt], acc[mt][nt], 0, 0, 0);
        __syncthreads();
    }

    // epilogue: C/D layout col=lane&15, row=(lane>>4)*4+r
    #pragma unroll
    for (int mt = 0; mt < 4; ++mt) {
        #pragma unroll
        for (int nt = 0; nt < 4; ++nt) {
            int col = nblk + wn * 64 + nt * 16 + ln;
            float bv = BIAS ? bias[col] : 0.f;
            #pragma unroll
            for (int r = 0; r < 4; ++r) {
                int row = mblk + wm * 64 + mt * 16 + q * 4 + r;
                C[(size_t)row * N + col] = acc[mt][nt][r] + bv;
            }
        }
    }
}

// ---------------- causal depthwise conv (k=4) + silu ---------------------------
// u_pre[m,d] = xz[m*4096 + d]; u[m,d] = silu(sum_{j=0..3} w[d,3-j]*u_pre[m-j,d])
__global__ void conv_silu_kernel(const float* __restrict__ xz,
                                 const float* __restrict__ conv_w,
                                 float* __restrict__ u) {
    int idx = blockIdx.x * blockDim.x + threadIdx.x;   // m*2048 + d
    int d = idx & (D_INNER - 1);
    int m = idx >> 11;
    int l = m & (SEQ - 1);
    const float* w = conv_w + d * 4;
    float s = 0.f;
    #pragma unroll
    for (int j = 0; j < 4; ++j) {
        if (l - j >= 0) s += w[3 - j] * xz[(size_t)(m - j) * 4096 + d];
    }
    float sig = 1.f / (1.f + __expf(-s));
    u[idx] = s * sig;
}

// ---------------- x_proj: x_dbl[m,n] = dot(u[m,:], xw[n,:]), n in [0,17) -------
__global__ void xproj_kernel(const float* __restrict__ u,
                             const float* __restrict__ xw,
                             float* __restrict__ dt_in,
                             float* __restrict__ Bm) {
    __shared__ __align__(16) float su[D_INNER];
    int m = blockIdx.x;
    int tid = threadIdx.x;
    const float* ur = u + (size_t)m * D_INNER;
    for (int i = tid; i < D_INNER / 4; i += 256)
        ((float4*)su)[i] = ((const float4*)ur)[i];
    __syncthreads();
    int wid = tid >> 6, lane = tid & 63;
    for (int n = wid; n < D_STATE + 1; n += 4) {
        const float* wr = xw + (size_t)n * D_INNER;
        float s = 0.f;
        for (int k = lane; k < D_INNER; k += 64) s += su[k] * wr[k];
        s += __shfl_xor(s, 32); s += __shfl_xor(s, 16); s += __shfl_xor(s, 8);
        s += __shfl_xor(s, 4);  s += __shfl_xor(s, 2);  s += __shfl_xor(s, 1);
        if (lane == 0) {
            if (n == 0) dt_in[m] = s;
            else        Bm[(size_t)m * D_STATE + (n - 1)] = s;
        }
    }
}

// ---------------- selective scan ----------------------------------------------
// thread = (b, d_local, n): 256 blocks (b x 128 d-groups) * 256 threads (16d x 16n)
// h = exp(A*delta)*h + delta*B ; ys[b,l,d] = sum_n h*B  (delta fused via softplus)
__global__ void scan_kernel(const float* __restrict__ dt_in,
                            const float* __restrict__ Bm,
                            const float* __restrict__ dt_w,
                            const float* __restrict__ dt_b,
                            const float* __restrict__ A_param,
                            float* __restrict__ ys) {
    __shared__ float sdt[256];
    __shared__ float sB[256 * D_STATE];
    int b  = blockIdx.x >> 7;
    int d0 = (blockIdx.x & 127) << 4;
    int tid = threadIdx.x;
    int dl = tid >> 4, n = tid & 15;
    int d = d0 + dl;

    float dtw = dt_w[d], dtb = dt_b[d];
    float aA  = -__expf(A_param[d * D_STATE + n]);   // A = -exp(A_param)
    float h   = 0.f;
    size_t ybase = (size_t)b * SEQ * D_INNER + d;

    for (int c = 0; c < SEQ / 256; ++c) {
        int t0 = c * 256;
        sdt[tid] = dt_in[b * SEQ + t0 + tid];
        const float4* g4 = (const float4*)(Bm + ((size_t)b * SEQ + t0) * D_STATE);
        float4* s4 = (float4*)sB;
        #pragma unroll
        for (int j = 0; j < 4; ++j) s4[tid + 256 * j] = g4[tid + 256 * j];
        __syncthreads();

        for (int t = 0; t < 256; ++t) {
            float xv = sdt[t] * dtw + dtb;
            float sp = fmaxf(xv, 0.f) + __logf(1.f + __expf(-fabsf(xv))); // softplus
            float Bv = sB[t * D_STATE + n];
            h = __expf(aA * sp) * h + sp * Bv;
            float p = h * Bv;
            p += __shfl_xor(p, 1); p += __shfl_xor(p, 2);
            p += __shfl_xor(p, 4); p += __shfl_xor(p, 8);
            if (n == 0) ys[ybase + (size_t)(t0 + t) * D_INNER] = p;
        }
        __syncthreads();
    }
}

// ---------------- ypost: yp = (ys + u*D) * silu(z)  -> bf16 --------------------
__global__ void ypost_kernel(const float* __restrict__ ys,
                             const float* __restrict__ u,
                             const float* __restrict__ xz,
                             const float* __restrict__ Dp,
                             unsigned short* __restrict__ ypb) {
    int idx = blockIdx.x * blockDim.x + threadIdx.x;   // m*2048+d
    int d = idx & (D_INNER - 1);
    int m = idx >> 11;
    float z  = xz[(size_t)m * 4096 + D_INNER + d];
    float sz = z / (1.f + __expf(-z));
    float yv = (ys[idx] + u[idx] * Dp[d]) * sz;
    ypb[idx] = f2bf(yv);
}

// ---------------- launch -------------------------------------------------------
extern "C" void kernel_launch(void* const* d_in, const int* in_sizes, int n_in,
                              void* d_out, int out_size, void* d_ws, size_t ws_size,
                              hipStream_t stream) {
    const float* x         = (const float*)d_in[0];   // (2,1024,1024)
    const float* in_proj_w = (const float*)d_in[1];   // (4096,1024)
    const float* conv_w    = (const float*)d_in[2];   // (2048,1,4)
    const float* x_proj_w  = (const float*)d_in[3];   // (17,2048)
    const float* dt_w      = (const float*)d_in[4];   // (2048,1)
    const float* dt_b      = (const float*)d_in[5];   // (2048,)
    const float* A_param   = (const float*)d_in[6];   // (2048,16)
    const float* D_param   = (const float*)d_in[7];   // (2048,)
    const float* out_w     = (const float*)d_in[8];   // (1024,2048)
    const float* out_b     = (const float*)d_in[9];   // (1024,)
    float* out = (float*)d_out;                       // (2,1024,1024)

    // workspace layout (bytes), all 16B-aligned
    char* ws = (char*)d_ws;
    unsigned short* xb  = (unsigned short*)(ws);                      //  4 MB (2048x1024)
    unsigned short* wbi = (unsigned short*)(ws + (4u << 20));         //  8 MB (4096x1024)
    unsigned short* wbo = (unsigned short*)(ws + (12u << 20));        //  4 MB (1024x2048)
    float*          xz  = (float*)(ws + (16u << 20));                 // 32 MB (2048x4096)
    float*          u   = (float*)(ws + (48u << 20));                 // 16 MB (2048x2048)
    float*          dti = (float*)(ws + (64u << 20));                 //  8 KB (2048)
    float*          Bm  = (float*)(ws + (64u << 20) + (256u << 10));  // 128 KB (2048x16)
    float*          ys  = (float*)(ws + (65u << 20));                 // 16 MB (2048x2048)
    unsigned short* ypb = (unsigned short*)(ws + (81u << 20));        //  8 MB (2048x2048)
    // total 89 MB

    // 1) fp32 -> bf16 for GEMM operands
    cvt_bf16_kernel<<<dim3(MROWS * D_MODEL / 1024), 256, 0, stream>>>(x, xb, MROWS * D_MODEL);
    cvt_bf16_kernel<<<dim3(2 * D_INNER * D_MODEL / 1024), 256, 0, stream>>>(in_proj_w, wbi, 2 * D_INNER * D_MODEL);
    cvt_bf16_kernel<<<dim3(D_MODEL * D_INNER / 1024), 256, 0, stream>>>(out_w, wbo, D_MODEL * D_INNER);

    // 2) xz = x @ in_proj_w^T   (M=2048, N=4096, K=1024)
    gemm_bf16_kernel<false><<<dim3(4096 / 128, MROWS / 128), 256, 0, stream>>>(
        xb, wbi, xz, nullptr, MROWS, 2 * D_INNER, D_MODEL);

    // 3) u = silu(causal_conv(xz[:, :2048]))
    conv_silu_kernel<<<dim3(MROWS * D_INNER / 256), 256, 0, stream>>>(xz, conv_w, u);

    // 4) x_dbl = u @ x_proj_w^T -> dt_in, Bmat
    xproj_kernel<<<dim3(MROWS), 256, 0, stream>>>(u, x_proj_w, dti, Bm);

    // 5) selective scan -> ys
    scan_kernel<<<dim3(BATCH * (D_INNER / 16)), 256, 0, stream>>>(dti, Bm, dt_w, dt_b, A_param, ys);

    // 6) yp = (ys + u*D) * silu(z) -> bf16
    ypost_kernel<<<dim3(MROWS * D_INNER / 256), 256, 0, stream>>>(ys, u, xz, D_param, ypb);

    // 7) out = yp @ out_w^T + out_b   (M=2048, N=1024, K=2048)
    gemm_bf16_kernel<true><<<dim3(1024 / 128, MROWS / 128), 256, 0, stream>>>(
        ypb, wbo, out, out_b, MROWS, D_MODEL, D_INNER);
}

// Round 2
// 301.617 us; speedup vs baseline: 1.7641x; 1.7641x over previous
//
#include <hip/hip_runtime.h>
#include <stdint.h>
#include <stddef.h>

#define D_MODEL 1024
#define D_STATE 16
#define D_INNER 2048
#define BATCH   2
#define SEQ     1024
#define MROWS   (BATCH*SEQ)   // 2048

// chunked scan config
#define NCH 16                // chunks along seq
#define TCH (SEQ/NCH)         // 64 steps per chunk
#define NREC (BATCH*D_INNER*D_STATE)  // 65536 recurrences

typedef __bf16 bf16x8 __attribute__((ext_vector_type(8)));
typedef float  f32x4  __attribute__((ext_vector_type(4)));

__device__ __forceinline__ unsigned short f2bf(float f) {
    unsigned int u = __float_as_uint(f);
    u += 0x7fffu + ((u >> 16) & 1u);      // RNE
    return (unsigned short)(u >> 16);
}

// ---------------- fp32 -> bf16 conversion (x, in_proj_w, out_w) ----------------
__global__ void cvt_bf16_kernel(const float* __restrict__ src,
                                unsigned short* __restrict__ dst, int n) {
    int i = (blockIdx.x * blockDim.x + threadIdx.x) * 4;
    if (i < n) {
        float4 v = *(const float4*)(src + i);
        ushort4 o;
        o.x = f2bf(v.x); o.y = f2bf(v.y); o.z = f2bf(v.z); o.w = f2bf(v.w);
        *(ushort4*)(dst + i) = o;
    }
}

// ---------------- bf16 MFMA GEMM: C[m,n] = sum_k A[m,k]*Bw[n,k] (+bias[n]) -----
// A: M x K bf16 row-major, Bw: N x K bf16 row-major, C: M x N fp32.
// 128x128 block tile, BK=32, 256 threads (4 waves, 2x2, each 64x64).
template<bool BIAS>
__global__ void gemm_bf16_kernel(const unsigned short* __restrict__ A,
                                 const unsigned short* __restrict__ Bw,
                                 float* __restrict__ C,
                                 const float* __restrict__ bias,
                                 int M, int N, int K) {
    // padded row stride 40 bf16 (80B = odd multiple of 16B -> 2-way on b128 reads)
    __shared__ __align__(16) unsigned short Al[128 * 40];
    __shared__ __align__(16) unsigned short Bl[128 * 40];

    const int tid  = threadIdx.x;
    const int lane = tid & 63;
    const int wid  = tid >> 6;
    const int wm   = wid >> 1;        // 0..1
    const int wn   = wid & 1;         // 0..1
    const int ln   = lane & 15;
    const int q    = lane >> 4;       // 0..3
    const int mblk = blockIdx.y * 128;
    const int nblk = blockIdx.x * 128;

    f32x4 acc[4][4] = {};

    for (int k0 = 0; k0 < K; k0 += 32) {
        #pragma unroll
        for (int h = 0; h < 2; ++h) {
            int c    = tid + h * 256;
            int row  = c >> 2;
            int part = c & 3;
            uint4 va = *(const uint4*)(A  + (size_t)(mblk + row) * K + k0 + part * 8);
            *(uint4*)(Al + row * 40 + part * 8) = va;
            uint4 vb = *(const uint4*)(Bw + (size_t)(nblk + row) * K + k0 + part * 8);
            *(uint4*)(Bl + row * 40 + part * 8) = vb;
        }
        __syncthreads();

        bf16x8 af[4], bfr[4];
        #pragma unroll
        for (int mt = 0; mt < 4; ++mt)
            af[mt] = *(const bf16x8*)(Al + (wm * 64 + mt * 16 + ln) * 40 + q * 8);
        #pragma unroll
        for (int nt = 0; nt < 4; ++nt)
            bfr[nt] = *(const bf16x8*)(Bl + (wn * 64 + nt * 16 + ln) * 40 + q * 8);

        #pragma unroll
        for (int mt = 0; mt < 4; ++mt)
            #pragma unroll
            for (int nt = 0; nt < 4; ++nt)
                acc[mt][nt] = __builtin_amdgcn_mfma_f32_16x16x32_bf16(
                    af[mt], bfr[nt], acc[mt][nt], 0, 0, 0);
        __syncthreads();
    }

    #pragma unroll
    for (int mt = 0; mt < 4; ++mt) {
        #pragma unroll
        for (int nt = 0; nt < 4; ++nt) {
            int col = nblk + wn * 64 + nt * 16 + ln;
            float bv = BIAS ? bias[col] : 0.f;
            #pragma unroll
            for (int r = 0; r < 4; ++r) {
                int row = mblk + wm * 64 + mt * 16 + q * 4 + r;
                C[(size_t)row * N + col] = acc[mt][nt][r] + bv;
            }
        }
    }
}

// ---------------- causal depthwise conv (k=4) + silu ---------------------------
__global__ void conv_silu_kernel(const float* __restrict__ xz,
                                 const float* __restrict__ conv_w,
                                 float* __restrict__ u) {
    int idx = blockIdx.x * blockDim.x + threadIdx.x;   // m*2048 + d
    int d = idx & (D_INNER - 1);
    int m = idx >> 11;
    int l = m & (SEQ - 1);
    const float* w = conv_w + d * 4;
    float s = 0.f;
    #pragma unroll
    for (int j = 0; j < 4; ++j) {
        if (l - j >= 0) s += w[3 - j] * xz[(size_t)(m - j) * 4096 + d];
    }
    float sig = 1.f / (1.f + __expf(-s));
    u[idx] = s * sig;
}

// ---------------- x_proj: x_dbl[m,n] = dot(u[m,:], xw[n,:]), n in [0,17) -------
__global__ void xproj_kernel(const float* __restrict__ u,
                             const float* __restrict__ xw,
                             float* __restrict__ dt_in,
                             float* __restrict__ Bm) {
    __shared__ __align__(16) float su[D_INNER];
    int m = blockIdx.x;
    int tid = threadIdx.x;
    const float* ur = u + (size_t)m * D_INNER;
    for (int i = tid; i < D_INNER / 4; i += 256)
        ((float4*)su)[i] = ((const float4*)ur)[i];
    __syncthreads();
    int wid = tid >> 6, lane = tid & 63;
    for (int n = wid; n < D_STATE + 1; n += 4) {
        const float* wr = xw + (size_t)n * D_INNER;
        float s = 0.f;
        for (int k = lane; k < D_INNER; k += 64) s += su[k] * wr[k];
        s += __shfl_xor(s, 32); s += __shfl_xor(s, 16); s += __shfl_xor(s, 8);
        s += __shfl_xor(s, 4);  s += __shfl_xor(s, 2);  s += __shfl_xor(s, 1);
        if (lane == 0) {
            if (n == 0) dt_in[m] = s;
            else        Bm[(size_t)m * D_STATE + (n - 1)] = s;
        }
    }
}

// ---------------- chunked selective scan ---------------------------------------
// Recurrence per (b,d,n): h_t = exp(aA*sp_t)*h_{t-1} + sp_t*B_t, y_t = sum_n h_t*B_t.
// Pass A: per-chunk local scan S (h0=0) and decay P = exp(aA * sum_t sp_t).
// Pass B: serial combine over chunks -> h_in per chunk.
// Pass C: replay chunk with h_in, emit y.
// Thread = (b, d, chunk): all 16 n-states in registers, softplus computed once.

__device__ __forceinline__ float softplus_f(float xv) {
    return fmaxf(xv, 0.f) + __logf(1.f + __expf(-fabsf(xv)));
}

__global__ void scanA_kernel(const float* __restrict__ dt_in,
                             const float* __restrict__ Bm,
                             const float* __restrict__ dt_w,
                             const float* __restrict__ dt_b,
                             const float* __restrict__ A_param,
                             float* __restrict__ Pg,     // [NCH][NREC]
                             float* __restrict__ Sg) {   // [NCH][NREC]
    __shared__ float sdt[TCH];
    __shared__ float sB[TCH * D_STATE];
    const int tid = threadIdx.x;
    const int b = blockIdx.z, c = blockIdx.y;
    const int d = blockIdx.x * 256 + tid;

    if (tid < TCH) sdt[tid] = dt_in[b * SEQ + c * TCH + tid];
    ((float4*)sB)[tid] = ((const float4*)(Bm + ((size_t)(b * SEQ + c * TCH)) * D_STATE))[tid];
    __syncthreads();

    const float dtw = dt_w[d], dtb = dt_b[d];
    float aA[D_STATE], h[D_STATE];
    #pragma unroll
    for (int n4 = 0; n4 < 4; ++n4) {
        float4 ap = ((const float4*)(A_param + (size_t)d * D_STATE))[n4];
        aA[n4*4+0] = -__expf(ap.x); aA[n4*4+1] = -__expf(ap.y);
        aA[n4*4+2] = -__expf(ap.z); aA[n4*4+3] = -__expf(ap.w);
    }
    #pragma unroll
    for (int n = 0; n < D_STATE; ++n) h[n] = 0.f;
    float tsum = 0.f;

    for (int t = 0; t < TCH; ++t) {
        float sp = softplus_f(sdt[t] * dtw + dtb);
        tsum += sp;
        #pragma unroll
        for (int n = 0; n < D_STATE; ++n) {
            float a = __expf(aA[n] * sp);
            h[n] = a * h[n] + sp * sB[t * D_STATE + n];
        }
    }

    size_t base = (size_t)c * NREC + ((size_t)(b * D_INNER + d)) * D_STATE;
    #pragma unroll
    for (int n4 = 0; n4 < 4; ++n4) {
        float4 pv, sv;
        pv.x = __expf(aA[n4*4+0] * tsum); pv.y = __expf(aA[n4*4+1] * tsum);
        pv.z = __expf(aA[n4*4+2] * tsum); pv.w = __expf(aA[n4*4+3] * tsum);
        sv.x = h[n4*4+0]; sv.y = h[n4*4+1]; sv.z = h[n4*4+2]; sv.w = h[n4*4+3];
        *(float4*)(Pg + base + n4 * 4) = pv;
        *(float4*)(Sg + base + n4 * 4) = sv;
    }
}

__global__ void scanB_kernel(const float* __restrict__ Pg,
                             const float* __restrict__ Sg,
                             float* __restrict__ Hin) {  // [NCH][NREC]
    int idx = blockIdx.x * 256 + threadIdx.x;   // recurrence id
    float h = 0.f;
    #pragma unroll
    for (int c = 0; c < NCH; ++c) {
        size_t o = (size_t)c * NREC + idx;
        Hin[o] = h;
        h = Pg[o] * h + Sg[o];
    }
}

__global__ void scanC_kernel(const float* __restrict__ dt_in,
                             const float* __restrict__ Bm,
                             const float* __restrict__ dt_w,
                             const float* __restrict__ dt_b,
                             const float* __restrict__ A_param,
                             const float* __restrict__ Hin,
                             float* __restrict__ ys) {
    __shared__ float sdt[TCH];
    __shared__ float sB[TCH * D_STATE];
    const int tid = threadIdx.x;
    const int b = blockIdx.z, c = blockIdx.y;
    const int d = blockIdx.x * 256 + tid;

    if (tid < TCH) sdt[tid] = dt_in[b * SEQ + c * TCH + tid];
    ((float4*)sB)[tid] = ((const float4*)(Bm + ((size_t)(b * SEQ + c * TCH)) * D_STATE))[tid];
    __syncthreads();

    const float dtw = dt_w[d], dtb = dt_b[d];
    float aA[D_STATE], h[D_STATE];
    #pragma unroll
    for (int n4 = 0; n4 < 4; ++n4) {
        float4 ap = ((const float4*)(A_param + (size_t)d * D_STATE))[n4];
        aA[n4*4+0] = -__expf(ap.x); aA[n4*4+1] = -__expf(ap.y);
        aA[n4*4+2] = -__expf(ap.z); aA[n4*4+3] = -__expf(ap.w);
    }
    size_t hbase = (size_t)c * NREC + ((size_t)(b * D_INNER + d)) * D_STATE;
    #pragma unroll
    for (int n4 = 0; n4 < 4; ++n4) {
        float4 hv = *(const float4*)(Hin + hbase + n4 * 4);
        h[n4*4+0] = hv.x; h[n4*4+1] = hv.y; h[n4*4+2] = hv.z; h[n4*4+3] = hv.w;
    }

    size_t ybase = ((size_t)b * SEQ + c * TCH) * D_INNER + d;
    for (int t = 0; t < TCH; ++t) {
        float sp = softplus_f(sdt[t] * dtw + dtb);
        float y0 = 0.f, y1 = 0.f, y2 = 0.f, y3 = 0.f;
        #pragma unroll
        for (int n4 = 0; n4 < 4; ++n4) {
            #pragma unroll
            for (int j = 0; j < 4; ++j) {
                int n = n4 * 4 + j;
                float Bv = sB[t * D_STATE + n];
                float a = __expf(aA[n] * sp);
                h[n] = a * h[n] + sp * Bv;
                float p = h[n] * Bv;
                if (n4 == 0) y0 += p; else if (n4 == 1) y1 += p;
                else if (n4 == 2) y2 += p; else y3 += p;
            }
        }
        ys[ybase + (size_t)t * D_INNER] = (y0 + y1) + (y2 + y3);
    }
}

// ---------------- ypost: yp = (ys + u*D) * silu(z)  -> bf16 --------------------
__global__ void ypost_kernel(const float* __restrict__ ys,
                             const float* __restrict__ u,
                             const float* __restrict__ xz,
                             const float* __restrict__ Dp,
                             unsigned short* __restrict__ ypb) {
    int idx = blockIdx.x * blockDim.x + threadIdx.x;   // m*2048+d
    int d = idx & (D_INNER - 1);
    int m = idx >> 11;
    float z  = xz[(size_t)m * 4096 + D_INNER + d];
    float sz = z / (1.f + __expf(-z));
    float yv = (ys[idx] + u[idx] * Dp[d]) * sz;
    ypb[idx] = f2bf(yv);
}

// ---------------- launch -------------------------------------------------------
extern "C" void kernel_launch(void* const* d_in, const int* in_sizes, int n_in,
                              void* d_out, int out_size, void* d_ws, size_t ws_size,
                              hipStream_t stream) {
    const float* x         = (const float*)d_in[0];
    const float* in_proj_w = (const float*)d_in[1];
    const float* conv_w    = (const float*)d_in[2];
    const float* x_proj_w  = (const float*)d_in[3];
    const float* dt_w      = (const float*)d_in[4];
    const float* dt_b      = (const float*)d_in[5];
    const float* A_param   = (const float*)d_in[6];
    const float* D_param   = (const float*)d_in[7];
    const float* out_w     = (const float*)d_in[8];
    const float* out_b     = (const float*)d_in[9];
    float* out = (float*)d_out;

    // workspace layout (bytes), all 16B-aligned.
    // [0,12MB): xb(4)+wbi(8) during in_proj GEMM; REUSED as Pg/Sg/Hin for the
    // scan (gemm1 completes before scanA launches — pure dataflow, capture-safe).
    char* ws = (char*)d_ws;
    unsigned short* xb  = (unsigned short*)(ws);                      //  4 MB
    unsigned short* wbi = (unsigned short*)(ws + (4u << 20));         //  8 MB
    unsigned short* wbo = (unsigned short*)(ws + (12u << 20));        //  4 MB
    float*          xz  = (float*)(ws + (16u << 20));                 // 32 MB
    float*          u   = (float*)(ws + (48u << 20));                 // 16 MB
    float*          dti = (float*)(ws + (64u << 20));                 //  8 KB
    float*          Bm  = (float*)(ws + (64u << 20) + (256u << 10));  // 128 KB
    float*          ys  = (float*)(ws + (65u << 20));                 // 16 MB
    unsigned short* ypb = (unsigned short*)(ws + (81u << 20));        //  8 MB
    float*          Pg  = (float*)(ws);                               //  4 MB (reuse xb)
    float*          Sg  = (float*)(ws + (4u << 20));                  //  4 MB (reuse wbi lo)
    float*          Hin = (float*)(ws + (8u << 20));                  //  4 MB (reuse wbi hi)

    // 1) fp32 -> bf16 for GEMM operands
    cvt_bf16_kernel<<<dim3(MROWS * D_MODEL / 1024), 256, 0, stream>>>(x, xb, MROWS * D_MODEL);
    cvt_bf16_kernel<<<dim3(2 * D_INNER * D_MODEL / 1024), 256, 0, stream>>>(in_proj_w, wbi, 2 * D_INNER * D_MODEL);
    cvt_bf16_kernel<<<dim3(D_MODEL * D_INNER / 1024), 256, 0, stream>>>(out_w, wbo, D_MODEL * D_INNER);

    // 2) xz = x @ in_proj_w^T   (M=2048, N=4096, K=1024)
    gemm_bf16_kernel<false><<<dim3(4096 / 128, MROWS / 128), 256, 0, stream>>>(
        xb, wbi, xz, nullptr, MROWS, 2 * D_INNER, D_MODEL);

    // 3) u = silu(causal_conv(xz[:, :2048]))
    conv_silu_kernel<<<dim3(MROWS * D_INNER / 256), 256, 0, stream>>>(xz, conv_w, u);

    // 4) x_dbl = u @ x_proj_w^T -> dt_in, Bmat
    xproj_kernel<<<dim3(MROWS), 256, 0, stream>>>(u, x_proj_w, dti, Bm);

    // 5) chunked selective scan -> ys
    scanA_kernel<<<dim3(D_INNER / 256, NCH, BATCH), 256, 0, stream>>>(
        dti, Bm, dt_w, dt_b, A_param, Pg, Sg);
    scanB_kernel<<<dim3(NREC / 256), 256, 0, stream>>>(Pg, Sg, Hin);
    scanC_kernel<<<dim3(D_INNER / 256, NCH, BATCH), 256, 0, stream>>>(
        dti, Bm, dt_w, dt_b, A_param, Hin, ys);

    // 6) yp = (ys + u*D) * silu(z) -> bf16
    ypost_kernel<<<dim3(MROWS * D_INNER / 256), 256, 0, stream>>>(ys, u, xz, D_param, ypb);

    // 7) out = yp @ out_w^T + out_b   (M=2048, N=1024, K=2048)
    gemm_bf16_kernel<true><<<dim3(1024 / 128, MROWS / 128), 256, 0, stream>>>(
        ypb, wbo, out, out_b, MROWS, D_MODEL, D_INNER);
}

// Round 3
// 254.513 us; speedup vs baseline: 2.0906x; 1.1851x over previous
//
#include <hip/hip_runtime.h>
#include <stdint.h>
#include <stddef.h>

#define D_MODEL 1024
#define D_STATE 16
#define D_INNER 2048
#define BATCH   2
#define SEQ     1024
#define MROWS   (BATCH*SEQ)   // 2048

// chunked scan config
#define NCH 16
#define TCH (SEQ/NCH)         // 64
#define NREC (BATCH*D_INNER*D_STATE)  // 65536

// xproj k-split
#define XKS 8
#define XKC (D_INNER/XKS)     // 256

typedef __bf16 bf16x8 __attribute__((ext_vector_type(8)));
typedef float  f32x4  __attribute__((ext_vector_type(4)));

__device__ __forceinline__ unsigned short f2bf(float f) {
    unsigned int u = __float_as_uint(f);
    u += 0x7fffu + ((u >> 16) & 1u);      // RNE
    return (unsigned short)(u >> 16);
}

// async global -> LDS, 16B per lane; lptr must be wave-uniform (HW writes
// lane i at lptr + i*16). m97 pattern: 874 TF vs 517 without.
__device__ __forceinline__ void gl_lds16(const unsigned short* g, unsigned short* l) {
    __builtin_amdgcn_global_load_lds(
        (const __attribute__((address_space(1))) unsigned int*)g,
        (__attribute__((address_space(3))) unsigned int*)l, 16, 0, 0);
}

// ---------------- fp32 -> bf16 conversion ------------------------------------
__global__ void cvt_bf16_kernel(const float* __restrict__ src,
                                unsigned short* __restrict__ dst, int n) {
    int i = (blockIdx.x * blockDim.x + threadIdx.x) * 4;
    if (i < n) {
        float4 v = *(const float4*)(src + i);
        ushort4 o;
        o.x = f2bf(v.x); o.y = f2bf(v.y); o.z = f2bf(v.z); o.w = f2bf(v.w);
        *(ushort4*)(dst + i) = o;
    }
}

// x_proj_w (17x2048 fp32) -> padded 32x2048 bf16 (rows 17..31 = 0)
__global__ void cvt_xw_kernel(const float* __restrict__ xw,
                              unsigned short* __restrict__ wbp) {
    int id = blockIdx.x * 256 + threadIdx.x;   // 0..65535
    wbp[id] = (id < 17 * D_INNER) ? f2bf(xw[id]) : (unsigned short)0;
}

// ---------------- bf16 MFMA GEMM: C[m,n] = sum_k A[m,k]*Bw[n,k] (+bias[n]) -----
// 128x128 tile, BK=32, 256 thr (4 waves 2x2 of 64x64). global_load_lds staging,
// unpadded LDS stride 32 (required by the wave-uniform-base contract).
template<bool BIAS>
__global__ void gemm_bf16_kernel(const unsigned short* __restrict__ A,
                                 const unsigned short* __restrict__ Bw,
                                 float* __restrict__ C,
                                 const float* __restrict__ bias,
                                 int M, int N, int K) {
    __shared__ __align__(16) unsigned short Al[128 * 32];
    __shared__ __align__(16) unsigned short Bl[128 * 32];

    const int tid  = threadIdx.x;
    const int lane = tid & 63;
    const int wid  = tid >> 6;
    const int wm   = wid >> 1;
    const int wn   = wid & 1;
    const int ln   = lane & 15;
    const int q    = lane >> 4;
    const int mblk = blockIdx.y * 128;
    const int nblk = blockIdx.x * 128;
    const int srow = lane >> 2;       // 0..15 within a 1KB chunk (16 rows x 64B)
    const int spart = lane & 3;       // 16B part within 64B row

    f32x4 acc[4][4] = {};

    for (int k0 = 0; k0 < K; k0 += 32) {
        #pragma unroll
        for (int h = 0; h < 2; ++h) {
            int j = wid * 2 + h;                  // chunk 0..7
            int row = j * 16 + srow;              // 0..127
            gl_lds16(A  + (size_t)(mblk + row) * K + k0 + spart * 8, Al + j * 512);
            gl_lds16(Bw + (size_t)(nblk + row) * K + k0 + spart * 8, Bl + j * 512);
        }
        __syncthreads();

        bf16x8 af[4], bfr[4];
        #pragma unroll
        for (int mt = 0; mt < 4; ++mt)
            af[mt] = *(const bf16x8*)(Al + (wm * 64 + mt * 16 + ln) * 32 + q * 8);
        #pragma unroll
        for (int nt = 0; nt < 4; ++nt)
            bfr[nt] = *(const bf16x8*)(Bl + (wn * 64 + nt * 16 + ln) * 32 + q * 8);

        #pragma unroll
        for (int mt = 0; mt < 4; ++mt)
            #pragma unroll
            for (int nt = 0; nt < 4; ++nt)
                acc[mt][nt] = __builtin_amdgcn_mfma_f32_16x16x32_bf16(
                    af[mt], bfr[nt], acc[mt][nt], 0, 0, 0);
        __syncthreads();
    }

    #pragma unroll
    for (int mt = 0; mt < 4; ++mt) {
        #pragma unroll
        for (int nt = 0; nt < 4; ++nt) {
            int col = nblk + wn * 64 + nt * 16 + ln;
            float bv = BIAS ? bias[col] : 0.f;
            #pragma unroll
            for (int r = 0; r < 4; ++r) {
                int row = mblk + wm * 64 + mt * 16 + q * 4 + r;
                C[(size_t)row * N + col] = acc[mt][nt][r] + bv;
            }
        }
    }
}

// ---------------- causal depthwise conv (k=4) + silu -> bf16 u -----------------
__global__ void conv_silu_kernel(const float* __restrict__ xz,
                                 const float* __restrict__ conv_w,
                                 unsigned short* __restrict__ ub) {
    int idx = blockIdx.x * blockDim.x + threadIdx.x;   // m*2048 + d
    int d = idx & (D_INNER - 1);
    int m = idx >> 11;
    int l = m & (SEQ - 1);
    const float* w = conv_w + d * 4;
    float s = 0.f;
    #pragma unroll
    for (int j = 0; j < 4; ++j) {
        if (l - j >= 0) s += w[3 - j] * xz[(size_t)(m - j) * 4096 + d];
    }
    float sig = 1.f / (1.f + __expf(-s));
    ub[idx] = f2bf(s * sig);
}

// ---------------- xproj mini-GEMM: part[ks][m][n] = ub[m,kslice] @ wbp[n,kslice]^T
// grid (XKS, MROWS/64), 256 thr. M-tile 64, N=32 (padded), BK=64, 4 K-iters.
__global__ void xproj_mfma_kernel(const unsigned short* __restrict__ ub,
                                  const unsigned short* __restrict__ wbp,
                                  float* __restrict__ part) {
    __shared__ __align__(16) unsigned short Al[64 * 64];  // 8KB
    __shared__ __align__(16) unsigned short Bl[32 * 64];  // 4KB

    const int tid  = threadIdx.x;
    const int lane = tid & 63;
    const int wid  = tid >> 6;
    const int ln   = lane & 15;
    const int q    = lane >> 4;
    const int m0   = blockIdx.y * 64;
    const int ks   = blockIdx.x;
    const int srow = lane >> 3;       // 0..7 within 1KB chunk (8 rows x 128B)
    const int spart = lane & 7;       // 16B part within 128B row

    f32x4 acc[2] = {};

    for (int it = 0; it < 4; ++it) {
        int k0 = ks * XKC + it * 64;
        #pragma unroll
        for (int h = 0; h < 2; ++h) {
            int j = wid * 2 + h;                  // 0..7
            int row = j * 8 + srow;               // 0..63
            gl_lds16(ub + (size_t)(m0 + row) * D_INNER + k0 + spart * 8, Al + j * 512);
        }
        {
            int row = wid * 8 + srow;             // 0..31
            gl_lds16(wbp + (size_t)row * D_INNER + k0 + spart * 8, Bl + wid * 512);
        }
        __syncthreads();

        bf16x8 af[2], bfr[2][2];
        #pragma unroll
        for (int kh = 0; kh < 2; ++kh) {
            af[kh] = *(const bf16x8*)(Al + (wid * 16 + ln) * 64 + kh * 32 + q * 8);
            bfr[0][kh] = *(const bf16x8*)(Bl + (0 * 16 + ln) * 64 + kh * 32 + q * 8);
            bfr[1][kh] = *(const bf16x8*)(Bl + (1 * 16 + ln) * 64 + kh * 32 + q * 8);
        }
        #pragma unroll
        for (int kh = 0; kh < 2; ++kh) {
            acc[0] = __builtin_amdgcn_mfma_f32_16x16x32_bf16(af[kh], bfr[0][kh], acc[0], 0, 0, 0);
            acc[1] = __builtin_amdgcn_mfma_f32_16x16x32_bf16(af[kh], bfr[1][kh], acc[1], 0, 0, 0);
        }
        __syncthreads();
    }

    #pragma unroll
    for (int nf = 0; nf < 2; ++nf) {
        #pragma unroll
        for (int r = 0; r < 4; ++r) {
            int m = m0 + wid * 16 + q * 4 + r;
            part[((size_t)ks * MROWS + m) * 32 + nf * 16 + ln] = acc[nf][r];
        }
    }
}

__global__ void xproj_reduce_kernel(const float* __restrict__ part,
                                    float* __restrict__ dti,
                                    float* __restrict__ Bm) {
    int id = blockIdx.x * 256 + threadIdx.x;   // m*32+n
    int m = id >> 5, n = id & 31;
    float s = 0.f;
    #pragma unroll
    for (int ks = 0; ks < XKS; ++ks) s += part[(size_t)ks * MROWS * 32 + id];
    if (n == 0) dti[m] = s;
    else if (n < 17) Bm[(size_t)m * D_STATE + (n - 1)] = s;
}

// ---------------- chunked selective scan ---------------------------------------
__device__ __forceinline__ float softplus_f(float xv) {
    return fmaxf(xv, 0.f) + __logf(1.f + __expf(-fabsf(xv)));
}

__global__ void scanA_kernel(const float* __restrict__ dt_in,
                             const float* __restrict__ Bm,
                             const float* __restrict__ dt_w,
                             const float* __restrict__ dt_b,
                             const float* __restrict__ A_param,
                             float* __restrict__ Pg,
                             float* __restrict__ Sg) {
    __shared__ float sdt[TCH];
    __shared__ float sB[TCH * D_STATE];
    const int tid = threadIdx.x;
    const int b = blockIdx.z, c = blockIdx.y;
    const int d = blockIdx.x * 256 + tid;

    if (tid < TCH) sdt[tid] = dt_in[b * SEQ + c * TCH + tid];
    ((float4*)sB)[tid] = ((const float4*)(Bm + ((size_t)(b * SEQ + c * TCH)) * D_STATE))[tid];
    __syncthreads();

    const float dtw = dt_w[d], dtb = dt_b[d];
    float aA[D_STATE], h[D_STATE];
    #pragma unroll
    for (int n4 = 0; n4 < 4; ++n4) {
        float4 ap = ((const float4*)(A_param + (size_t)d * D_STATE))[n4];
        aA[n4*4+0] = -__expf(ap.x); aA[n4*4+1] = -__expf(ap.y);
        aA[n4*4+2] = -__expf(ap.z); aA[n4*4+3] = -__expf(ap.w);
    }
    #pragma unroll
    for (int n = 0; n < D_STATE; ++n) h[n] = 0.f;
    float tsum = 0.f;

    for (int t = 0; t < TCH; ++t) {
        float sp = softplus_f(sdt[t] * dtw + dtb);
        tsum += sp;
        #pragma unroll
        for (int n = 0; n < D_STATE; ++n) {
            float a = __expf(aA[n] * sp);
            h[n] = a * h[n] + sp * sB[t * D_STATE + n];
        }
    }

    size_t base = (size_t)c * NREC + ((size_t)(b * D_INNER + d)) * D_STATE;
    #pragma unroll
    for (int n4 = 0; n4 < 4; ++n4) {
        float4 pv, sv;
        pv.x = __expf(aA[n4*4+0] * tsum); pv.y = __expf(aA[n4*4+1] * tsum);
        pv.z = __expf(aA[n4*4+2] * tsum); pv.w = __expf(aA[n4*4+3] * tsum);
        sv.x = h[n4*4+0]; sv.y = h[n4*4+1]; sv.z = h[n4*4+2]; sv.w = h[n4*4+3];
        *(float4*)(Pg + base + n4 * 4) = pv;
        *(float4*)(Sg + base + n4 * 4) = sv;
    }
}

__global__ void scanB_kernel(const float* __restrict__ Pg,
                             const float* __restrict__ Sg,
                             float* __restrict__ Hin) {
    int idx = blockIdx.x * 256 + threadIdx.x;
    float h = 0.f;
    #pragma unroll
    for (int c = 0; c < NCH; ++c) {
        size_t o = (size_t)c * NREC + idx;
        Hin[o] = h;
        h = Pg[o] * h + Sg[o];
    }
}

__global__ void scanC_kernel(const float* __restrict__ dt_in,
                             const float* __restrict__ Bm,
                             const float* __restrict__ dt_w,
                             const float* __restrict__ dt_b,
                             const float* __restrict__ A_param,
                             const float* __restrict__ Hin,
                             float* __restrict__ ys) {
    __shared__ float sdt[TCH];
    __shared__ float sB[TCH * D_STATE];
    const int tid = threadIdx.x;
    const int b = blockIdx.z, c = blockIdx.y;
    const int d = blockIdx.x * 256 + tid;

    if (tid < TCH) sdt[tid] = dt_in[b * SEQ + c * TCH + tid];
    ((float4*)sB)[tid] = ((const float4*)(Bm + ((size_t)(b * SEQ + c * TCH)) * D_STATE))[tid];
    __syncthreads();

    const float dtw = dt_w[d], dtb = dt_b[d];
    float aA[D_STATE], h[D_STATE];
    #pragma unroll
    for (int n4 = 0; n4 < 4; ++n4) {
        float4 ap = ((const float4*)(A_param + (size_t)d * D_STATE))[n4];
        aA[n4*4+0] = -__expf(ap.x); aA[n4*4+1] = -__expf(ap.y);
        aA[n4*4+2] = -__expf(ap.z); aA[n4*4+3] = -__expf(ap.w);
    }
    size_t hbase = (size_t)c * NREC + ((size_t)(b * D_INNER + d)) * D_STATE;
    #pragma unroll
    for (int n4 = 0; n4 < 4; ++n4) {
        float4 hv = *(const float4*)(Hin + hbase + n4 * 4);
        h[n4*4+0] = hv.x; h[n4*4+1] = hv.y; h[n4*4+2] = hv.z; h[n4*4+3] = hv.w;
    }

    size_t ybase = ((size_t)b * SEQ + c * TCH) * D_INNER + d;
    for (int t = 0; t < TCH; ++t) {
        float sp = softplus_f(sdt[t] * dtw + dtb);
        float y0 = 0.f, y1 = 0.f, y2 = 0.f, y3 = 0.f;
        #pragma unroll
        for (int n4 = 0; n4 < 4; ++n4) {
            #pragma unroll
            for (int j = 0; j < 4; ++j) {
                int n = n4 * 4 + j;
                float Bv = sB[t * D_STATE + n];
                float a = __expf(aA[n] * sp);
                h[n] = a * h[n] + sp * Bv;
                float p = h[n] * Bv;
                if (n4 == 0) y0 += p; else if (n4 == 1) y1 += p;
                else if (n4 == 2) y2 += p; else y3 += p;
            }
        }
        ys[ybase + (size_t)t * D_INNER] = (y0 + y1) + (y2 + y3);
    }
}

// ---------------- ypost: yp = (ys + u*D) * silu(z)  -> bf16 --------------------
__global__ void ypost_kernel(const float* __restrict__ ys,
                             const unsigned short* __restrict__ ub,
                             const float* __restrict__ xz,
                             const float* __restrict__ Dp,
                             unsigned short* __restrict__ ypb) {
    int idx = blockIdx.x * blockDim.x + threadIdx.x;   // m*2048+d
    int d = idx & (D_INNER - 1);
    int m = idx >> 11;
    float z  = xz[(size_t)m * 4096 + D_INNER + d];
    float sz = z / (1.f + __expf(-z));
    float uv = __uint_as_float((unsigned int)ub[idx] << 16);
    float yv = (ys[idx] + uv * Dp[d]) * sz;
    ypb[idx] = f2bf(yv);
}

// ---------------- launch -------------------------------------------------------
extern "C" void kernel_launch(void* const* d_in, const int* in_sizes, int n_in,
                              void* d_out, int out_size, void* d_ws, size_t ws_size,
                              hipStream_t stream) {
    const float* x         = (const float*)d_in[0];
    const float* in_proj_w = (const float*)d_in[1];
    const float* conv_w    = (const float*)d_in[2];
    const float* x_proj_w  = (const float*)d_in[3];
    const float* dt_w      = (const float*)d_in[4];
    const float* dt_b      = (const float*)d_in[5];
    const float* A_param   = (const float*)d_in[6];
    const float* D_param   = (const float*)d_in[7];
    const float* out_w     = (const float*)d_in[8];
    const float* out_b     = (const float*)d_in[9];
    float* out = (float*)d_out;

    // workspace layout; [0,12MB) holds GEMM1 operands then is reused by the scan
    // (pure dataflow order, capture-safe).
    char* ws = (char*)d_ws;
    unsigned short* xb  = (unsigned short*)(ws);                      //  4 MB
    unsigned short* wbi = (unsigned short*)(ws + (4u  << 20));        //  8 MB
    unsigned short* wbo = (unsigned short*)(ws + (12u << 20));        //  4 MB
    float*          xz  = (float*)(ws + (16u << 20));                 // 32 MB
    unsigned short* ub  = (unsigned short*)(ws + (48u << 20));        //  8 MB
    float*          dti = (float*)(ws + (56u << 20));                 //  8 KB (64K slot)
    float*          Bm  = (float*)(ws + (56u << 20) + (64u  << 10));  // 128 KB
    unsigned short* wbp = (unsigned short*)(ws + (56u << 20) + (192u << 10)); // 128 KB
    float*          xpt = (float*)(ws + (56u << 20) + (512u << 10));  //  2 MB partials
    float*          ys  = (float*)(ws + (59u << 20));                 // 16 MB
    unsigned short* ypb = (unsigned short*)(ws + (75u << 20));        //  8 MB
    float*          Pg  = (float*)(ws);                               //  4 MB (reuse xb)
    float*          Sg  = (float*)(ws + (4u << 20));                  //  4 MB (reuse wbi)
    float*          Hin = (float*)(ws + (8u << 20));                  //  4 MB (reuse wbi)
    // total 83 MB

    // 1) fp32 -> bf16 operands
    cvt_bf16_kernel<<<dim3(MROWS * D_MODEL / 1024), 256, 0, stream>>>(x, xb, MROWS * D_MODEL);
    cvt_bf16_kernel<<<dim3(2 * D_INNER * D_MODEL / 1024), 256, 0, stream>>>(in_proj_w, wbi, 2 * D_INNER * D_MODEL);
    cvt_bf16_kernel<<<dim3(D_MODEL * D_INNER / 1024), 256, 0, stream>>>(out_w, wbo, D_MODEL * D_INNER);
    cvt_xw_kernel<<<dim3(32 * D_INNER / 256), 256, 0, stream>>>(x_proj_w, wbp);

    // 2) xz = x @ in_proj_w^T   (M=2048, N=4096, K=1024)
    gemm_bf16_kernel<false><<<dim3(4096 / 128, MROWS / 128), 256, 0, stream>>>(
        xb, wbi, xz, nullptr, MROWS, 2 * D_INNER, D_MODEL);

    // 3) u = silu(causal_conv(xz[:, :2048])) -> bf16
    conv_silu_kernel<<<dim3(MROWS * D_INNER / 256), 256, 0, stream>>>(xz, conv_w, ub);

    // 4) x_dbl = u @ x_proj_w^T (k-split MFMA + reduce) -> dti, Bm
    xproj_mfma_kernel<<<dim3(XKS, MROWS / 64), 256, 0, stream>>>(ub, wbp, xpt);
    xproj_reduce_kernel<<<dim3(MROWS * 32 / 256), 256, 0, stream>>>(xpt, dti, Bm);

    // 5) chunked selective scan -> ys
    scanA_kernel<<<dim3(D_INNER / 256, NCH, BATCH), 256, 0, stream>>>(
        dti, Bm, dt_w, dt_b, A_param, Pg, Sg);
    scanB_kernel<<<dim3(NREC / 256), 256, 0, stream>>>(Pg, Sg, Hin);
    scanC_kernel<<<dim3(D_INNER / 256, NCH, BATCH), 256, 0, stream>>>(
        dti, Bm, dt_w, dt_b, A_param, Hin, ys);

    // 6) yp = (ys + u*D) * silu(z) -> bf16
    ypost_kernel<<<dim3(MROWS * D_INNER / 256), 256, 0, stream>>>(ys, ub, xz, D_param, ypb);

    // 7) out = yp @ out_w^T + out_b   (M=2048, N=1024, K=2048)
    gemm_bf16_kernel<true><<<dim3(1024 / 128, MROWS / 128), 256, 0, stream>>>(
        ypb, wbo, out, out_b, MROWS, D_MODEL, D_INNER);
}

// Round 4
// 238.786 us; speedup vs baseline: 2.2283x; 1.0659x over previous
//
#include <hip/hip_runtime.h>
#include <stdint.h>
#include <stddef.h>

#define D_MODEL 1024
#define D_STATE 16
#define D_INNER 2048
#define BATCH   2
#define SEQ     1024
#define MROWS   (BATCH*SEQ)   // 2048

// chunked scan config
#define NCH 32
#define TCH (SEQ/NCH)         // 32
#define NREC (BATCH*D_INNER*D_STATE)  // 65536

// xproj k-split
#define XKS 8
#define XKC (D_INNER/XKS)     // 256

typedef __bf16 bf16x8 __attribute__((ext_vector_type(8)));
typedef float  f32x4  __attribute__((ext_vector_type(4)));

__device__ __forceinline__ unsigned short f2bf(float f) {
    unsigned int u = __float_as_uint(f);
    u += 0x7fffu + ((u >> 16) & 1u);      // RNE
    return (unsigned short)(u >> 16);
}
__device__ __forceinline__ float bf2f(unsigned short v) {
    return __uint_as_float((unsigned int)v << 16);
}

// async global -> LDS, 16B/lane; LDS base wave-uniform (HW: lane i -> base+i*16)
__device__ __forceinline__ void gl_lds16(const unsigned short* g, unsigned short* l) {
    __builtin_amdgcn_global_load_lds(
        (const __attribute__((address_space(1))) unsigned int*)g,
        (__attribute__((address_space(3))) unsigned int*)l, 16, 0, 0);
}

// ---------------- fused fp32 -> bf16 conversions -------------------------------
// seg0: x (2M) -> xb | seg1: in_proj_w (4M) -> wbi | seg2: out_w (2M) -> wbo
// seg3: x_proj_w (17x2048, scalar+pad to 32x2048) -> wbp
__global__ void cvt_all_kernel(const float* __restrict__ x,
                               const float* __restrict__ w1,
                               const float* __restrict__ w2,
                               const float* __restrict__ xw,
                               unsigned short* __restrict__ xb,
                               unsigned short* __restrict__ wbi,
                               unsigned short* __restrict__ wbo,
                               unsigned short* __restrict__ wbp) {
    int blk = blockIdx.x, tid = threadIdx.x;
    if (blk < 8192) {
        const float* src; unsigned short* dst; int i;
        if (blk < 2048)      { src = x;  dst = xb;  i = blk * 1024 + tid * 4; }
        else if (blk < 6144) { src = w1; dst = wbi; i = (blk - 2048) * 1024 + tid * 4; }
        else                 { src = w2; dst = wbo; i = (blk - 6144) * 1024 + tid * 4; }
        float4 v = *(const float4*)(src + i);
        ushort4 o;
        o.x = f2bf(v.x); o.y = f2bf(v.y); o.z = f2bf(v.z); o.w = f2bf(v.w);
        *(ushort4*)(dst + i) = o;
    } else {
        int id = (blk - 8192) * 256 + tid;          // 0..65535
        wbp[id] = (id < 17 * D_INNER) ? f2bf(xw[id]) : (unsigned short)0;
    }
}

// ---------------- bf16 MFMA GEMM: C[m,n] = sum_k A[m,k]*Bw[n,k] (+bias[n]) -----
// 128 x NT tile (NT=128 or 64), BK=32, 256 thr (4 waves 2x2). global_load_lds
// staging, unpadded LDS stride 32 (wave-uniform-base contract).
template<int NT, bool BIAS>
__global__ void gemm_bf16_kernel(const unsigned short* __restrict__ A,
                                 const unsigned short* __restrict__ Bw,
                                 float* __restrict__ C,
                                 const float* __restrict__ bias,
                                 int M, int N, int K) {
    constexpr int NTW  = NT / 32;   // n-tiles per wave
    constexpr int BCHW = NT / 64;   // B staging chunks per wave
    __shared__ __align__(16) unsigned short Al[128 * 32];
    __shared__ __align__(16) unsigned short Bl[NT * 32];

    const int tid  = threadIdx.x;
    const int lane = tid & 63;
    const int wid  = tid >> 6;
    const int wm   = wid >> 1;
    const int wn   = wid & 1;
    const int ln   = lane & 15;
    const int q    = lane >> 4;
    const int mblk = blockIdx.y * 128;
    const int nblk = blockIdx.x * NT;
    const int srow = lane >> 2;       // 0..15 within 1KB chunk (16 rows x 64B)
    const int spart = lane & 3;       // 16B part within 64B row

    f32x4 acc[4][NTW] = {};

    for (int k0 = 0; k0 < K; k0 += 32) {
        #pragma unroll
        for (int h = 0; h < 2; ++h) {
            int j = wid * 2 + h;
            int row = j * 16 + srow;
            gl_lds16(A + (size_t)(mblk + row) * K + k0 + spart * 8, Al + j * 512);
        }
        #pragma unroll
        for (int h = 0; h < BCHW; ++h) {
            int j = wid * BCHW + h;
            int row = j * 16 + srow;
            gl_lds16(Bw + (size_t)(nblk + row) * K + k0 + spart * 8, Bl + j * 512);
        }
        __syncthreads();

        bf16x8 af[4], bfr[NTW];
        #pragma unroll
        for (int mt = 0; mt < 4; ++mt)
            af[mt] = *(const bf16x8*)(Al + (wm * 64 + mt * 16 + ln) * 32 + q * 8);
        #pragma unroll
        for (int nt = 0; nt < NTW; ++nt)
            bfr[nt] = *(const bf16x8*)(Bl + (wn * (NT/2) + nt * 16 + ln) * 32 + q * 8);

        #pragma unroll
        for (int mt = 0; mt < 4; ++mt)
            #pragma unroll
            for (int nt = 0; nt < NTW; ++nt)
                acc[mt][nt] = __builtin_amdgcn_mfma_f32_16x16x32_bf16(
                    af[mt], bfr[nt], acc[mt][nt], 0, 0, 0);
        __syncthreads();
    }

    #pragma unroll
    for (int mt = 0; mt < 4; ++mt) {
        #pragma unroll
        for (int nt = 0; nt < NTW; ++nt) {
            int col = nblk + wn * (NT/2) + nt * 16 + ln;
            float bv = BIAS ? bias[col] : 0.f;
            #pragma unroll
            for (int r = 0; r < 4; ++r) {
                int row = mblk + wm * 64 + mt * 16 + q * 4 + r;
                C[(size_t)row * N + col] = acc[mt][nt][r] + bv;
            }
        }
    }
}

// ---------------- causal depthwise conv (k=4) + silu -> bf16 u -----------------
__global__ void conv_silu_kernel(const float* __restrict__ xz,
                                 const float* __restrict__ conv_w,
                                 unsigned short* __restrict__ ub) {
    int idx = blockIdx.x * blockDim.x + threadIdx.x;   // m*2048 + d
    int d = idx & (D_INNER - 1);
    int m = idx >> 11;
    int l = m & (SEQ - 1);
    const float* w = conv_w + d * 4;
    float s = 0.f;
    #pragma unroll
    for (int j = 0; j < 4; ++j) {
        if (l - j >= 0) s += w[3 - j] * xz[(size_t)(m - j) * 4096 + d];
    }
    float sig = 1.f / (1.f + __expf(-s));
    ub[idx] = f2bf(s * sig);
}

// ---------------- xproj mini-GEMM: part[ks][m][n] = ub[m,ks-slice] @ wbp^T -----
__global__ void xproj_mfma_kernel(const unsigned short* __restrict__ ub,
                                  const unsigned short* __restrict__ wbp,
                                  float* __restrict__ part) {
    __shared__ __align__(16) unsigned short Al[64 * 64];  // 8KB
    __shared__ __align__(16) unsigned short Bl[32 * 64];  // 4KB

    const int tid  = threadIdx.x;
    const int lane = tid & 63;
    const int wid  = tid >> 6;
    const int ln   = lane & 15;
    const int q    = lane >> 4;
    const int m0   = blockIdx.y * 64;
    const int ks   = blockIdx.x;
    const int srow = lane >> 3;       // 0..7 within 1KB chunk (8 rows x 128B)
    const int spart = lane & 7;

    f32x4 acc[2] = {};

    for (int it = 0; it < 4; ++it) {
        int k0 = ks * XKC + it * 64;
        #pragma unroll
        for (int h = 0; h < 2; ++h) {
            int j = wid * 2 + h;
            int row = j * 8 + srow;
            gl_lds16(ub + (size_t)(m0 + row) * D_INNER + k0 + spart * 8, Al + j * 512);
        }
        {
            int row = wid * 8 + srow;
            gl_lds16(wbp + (size_t)row * D_INNER + k0 + spart * 8, Bl + wid * 512);
        }
        __syncthreads();

        bf16x8 af[2], bfr[2][2];
        #pragma unroll
        for (int kh = 0; kh < 2; ++kh) {
            af[kh] = *(const bf16x8*)(Al + (wid * 16 + ln) * 64 + kh * 32 + q * 8);
            bfr[0][kh] = *(const bf16x8*)(Bl + (0 * 16 + ln) * 64 + kh * 32 + q * 8);
            bfr[1][kh] = *(const bf16x8*)(Bl + (1 * 16 + ln) * 64 + kh * 32 + q * 8);
        }
        #pragma unroll
        for (int kh = 0; kh < 2; ++kh) {
            acc[0] = __builtin_amdgcn_mfma_f32_16x16x32_bf16(af[kh], bfr[0][kh], acc[0], 0, 0, 0);
            acc[1] = __builtin_amdgcn_mfma_f32_16x16x32_bf16(af[kh], bfr[1][kh], acc[1], 0, 0, 0);
        }
        __syncthreads();
    }

    #pragma unroll
    for (int nf = 0; nf < 2; ++nf) {
        #pragma unroll
        for (int r = 0; r < 4; ++r) {
            int m = m0 + wid * 16 + q * 4 + r;
            part[((size_t)ks * MROWS + m) * 32 + nf * 16 + ln] = acc[nf][r];
        }
    }
}

__global__ void xproj_reduce_kernel(const float* __restrict__ part,
                                    float* __restrict__ dti,
                                    float* __restrict__ Bm) {
    int id = blockIdx.x * 256 + threadIdx.x;   // m*32+n
    int m = id >> 5, n = id & 31;
    float s = 0.f;
    #pragma unroll
    for (int ks = 0; ks < XKS; ++ks) s += part[(size_t)ks * MROWS * 32 + id];
    if (n == 0) dti[m] = s;
    else if (n < 17) Bm[(size_t)m * D_STATE + (n - 1)] = s;
}

// ---------------- chunked selective scan ---------------------------------------
__device__ __forceinline__ float softplus_f(float xv) {
    return fmaxf(xv, 0.f) + __logf(1.f + __expf(-fabsf(xv)));
}

__global__ void scanA_kernel(const float* __restrict__ dt_in,
                             const float* __restrict__ Bm,
                             const float* __restrict__ dt_w,
                             const float* __restrict__ dt_b,
                             const float* __restrict__ A_param,
                             float* __restrict__ Pg,
                             float* __restrict__ Sg) {
    __shared__ float sdt[TCH];
    __shared__ float sB[TCH * D_STATE];
    const int tid = threadIdx.x;
    const int b = blockIdx.z, c = blockIdx.y;
    const int d = blockIdx.x * 256 + tid;

    if (tid < TCH) sdt[tid] = dt_in[b * SEQ + c * TCH + tid];
    if (tid < TCH * D_STATE / 4)
        ((float4*)sB)[tid] = ((const float4*)(Bm + ((size_t)(b * SEQ + c * TCH)) * D_STATE))[tid];
    __syncthreads();

    const float dtw = dt_w[d], dtb = dt_b[d];
    float aA[D_STATE], h[D_STATE];
    #pragma unroll
    for (int n4 = 0; n4 < 4; ++n4) {
        float4 ap = ((const float4*)(A_param + (size_t)d * D_STATE))[n4];
        aA[n4*4+0] = -__expf(ap.x); aA[n4*4+1] = -__expf(ap.y);
        aA[n4*4+2] = -__expf(ap.z); aA[n4*4+3] = -__expf(ap.w);
    }
    #pragma unroll
    for (int n = 0; n < D_STATE; ++n) h[n] = 0.f;
    float tsum = 0.f;

    for (int t = 0; t < TCH; ++t) {
        float sp = softplus_f(sdt[t] * dtw + dtb);
        tsum += sp;
        #pragma unroll
        for (int n = 0; n < D_STATE; ++n) {
            float a = __expf(aA[n] * sp);
            h[n] = a * h[n] + sp * sB[t * D_STATE + n];
        }
    }

    size_t base = (size_t)c * NREC + ((size_t)(b * D_INNER + d)) * D_STATE;
    #pragma unroll
    for (int n4 = 0; n4 < 4; ++n4) {
        float4 pv, sv;
        pv.x = __expf(aA[n4*4+0] * tsum); pv.y = __expf(aA[n4*4+1] * tsum);
        pv.z = __expf(aA[n4*4+2] * tsum); pv.w = __expf(aA[n4*4+3] * tsum);
        sv.x = h[n4*4+0]; sv.y = h[n4*4+1]; sv.z = h[n4*4+2]; sv.w = h[n4*4+3];
        *(float4*)(Pg + base + n4 * 4) = pv;
        *(float4*)(Sg + base + n4 * 4) = sv;
    }
}

__global__ void scanB_kernel(const float* __restrict__ Pg,
                             const float* __restrict__ Sg,
                             float* __restrict__ Hin) {
    int idx = blockIdx.x * 256 + threadIdx.x;
    float h = 0.f;
    #pragma unroll
    for (int c = 0; c < NCH; ++c) {
        size_t o = (size_t)c * NREC + idx;
        Hin[o] = h;
        h = Pg[o] * h + Sg[o];
    }
}

// scanC fused with ypost: yp[m,d] = (y + u*D) * silu(z) -> bf16, ys never stored.
__global__ void scanC_kernel(const float* __restrict__ dt_in,
                             const float* __restrict__ Bm,
                             const float* __restrict__ dt_w,
                             const float* __restrict__ dt_b,
                             const float* __restrict__ A_param,
                             const float* __restrict__ Hin,
                             const unsigned short* __restrict__ ub,
                             const float* __restrict__ xz,
                             const float* __restrict__ Dp,
                             unsigned short* __restrict__ ypb) {
    __shared__ float sdt[TCH];
    __shared__ float sB[TCH * D_STATE];
    const int tid = threadIdx.x;
    const int b = blockIdx.z, c = blockIdx.y;
    const int d = blockIdx.x * 256 + tid;

    if (tid < TCH) sdt[tid] = dt_in[b * SEQ + c * TCH + tid];
    if (tid < TCH * D_STATE / 4)
        ((float4*)sB)[tid] = ((const float4*)(Bm + ((size_t)(b * SEQ + c * TCH)) * D_STATE))[tid];
    __syncthreads();

    const float dtw = dt_w[d], dtb = dt_b[d];
    const float Dv = Dp[d];
    float aA[D_STATE], h[D_STATE];
    #pragma unroll
    for (int n4 = 0; n4 < 4; ++n4) {
        float4 ap = ((const float4*)(A_param + (size_t)d * D_STATE))[n4];
        aA[n4*4+0] = -__expf(ap.x); aA[n4*4+1] = -__expf(ap.y);
        aA[n4*4+2] = -__expf(ap.z); aA[n4*4+3] = -__expf(ap.w);
    }
    size_t hbase = (size_t)c * NREC + ((size_t)(b * D_INNER + d)) * D_STATE;
    #pragma unroll
    for (int n4 = 0; n4 < 4; ++n4) {
        float4 hv = *(const float4*)(Hin + hbase + n4 * 4);
        h[n4*4+0] = hv.x; h[n4*4+1] = hv.y; h[n4*4+2] = hv.z; h[n4*4+3] = hv.w;
    }

    const size_t mrow0 = (size_t)b * SEQ + c * TCH;
    for (int t = 0; t < TCH; ++t) {
        float sp = softplus_f(sdt[t] * dtw + dtb);
        float y0 = 0.f, y1 = 0.f, y2 = 0.f, y3 = 0.f;
        #pragma unroll
        for (int n4 = 0; n4 < 4; ++n4) {
            #pragma unroll
            for (int j = 0; j < 4; ++j) {
                int n = n4 * 4 + j;
                float Bv = sB[t * D_STATE + n];
                float a = __expf(aA[n] * sp);
                h[n] = a * h[n] + sp * Bv;
                float p = h[n] * Bv;
                if (n4 == 0) y0 += p; else if (n4 == 1) y1 += p;
                else if (n4 == 2) y2 += p; else y3 += p;
            }
        }
        float y = (y0 + y1) + (y2 + y3);
        size_t m = mrow0 + t;
        float z  = xz[m * 4096 + D_INNER + d];
        float sz = z / (1.f + __expf(-z));
        float uv = bf2f(ub[m * D_INNER + d]);
        ypb[m * D_INNER + d] = f2bf((y + uv * Dv) * sz);
    }
}

// ---------------- launch -------------------------------------------------------
extern "C" void kernel_launch(void* const* d_in, const int* in_sizes, int n_in,
                              void* d_out, int out_size, void* d_ws, size_t ws_size,
                              hipStream_t stream) {
    const float* x         = (const float*)d_in[0];
    const float* in_proj_w = (const float*)d_in[1];
    const float* conv_w    = (const float*)d_in[2];
    const float* x_proj_w  = (const float*)d_in[3];
    const float* dt_w      = (const float*)d_in[4];
    const float* dt_b      = (const float*)d_in[5];
    const float* A_param   = (const float*)d_in[6];
    const float* D_param   = (const float*)d_in[7];
    const float* out_w     = (const float*)d_in[8];
    const float* out_b     = (const float*)d_in[9];
    float* out = (float*)d_out;

    // workspace layout — all regions disjoint (91 MB of the 256 MiB ws)
    char* ws = (char*)d_ws;
    unsigned short* xb  = (unsigned short*)(ws);                      //  4 MB
    unsigned short* wbi = (unsigned short*)(ws + (4u  << 20));        //  8 MB
    unsigned short* wbo = (unsigned short*)(ws + (12u << 20));        //  4 MB
    float*          xz  = (float*)(ws + (16u << 20));                 // 32 MB
    unsigned short* ub  = (unsigned short*)(ws + (48u << 20));        //  8 MB
    float*          dti = (float*)(ws + (56u << 20));                 //  8 KB
    float*          Bm  = (float*)(ws + (56u << 20) + (64u  << 10));  // 128 KB
    unsigned short* wbp = (unsigned short*)(ws + (56u << 20) + (192u << 10)); // 128 KB
    float*          xpt = (float*)(ws + (56u << 20) + (512u << 10));  //  2 MB
    float*          Pg  = (float*)(ws + (59u << 20));                 //  8 MB
    float*          Sg  = (float*)(ws + (67u << 20));                 //  8 MB
    float*          Hin = (float*)(ws + (75u << 20));                 //  8 MB
    unsigned short* ypb = (unsigned short*)(ws + (83u << 20));        //  8 MB

    // 1) all fp32 -> bf16 conversions, one launch
    cvt_all_kernel<<<dim3(8448), 256, 0, stream>>>(
        x, in_proj_w, out_w, x_proj_w, xb, wbi, wbo, wbp);

    // 2) xz = x @ in_proj_w^T   (M=2048, N=4096, K=1024), 512 blocks
    gemm_bf16_kernel<128, false><<<dim3(4096 / 128, MROWS / 128), 256, 0, stream>>>(
        xb, wbi, xz, nullptr, MROWS, 2 * D_INNER, D_MODEL);

    // 3) u = silu(causal_conv(xz[:, :2048])) -> bf16
    conv_silu_kernel<<<dim3(MROWS * D_INNER / 256), 256, 0, stream>>>(xz, conv_w, ub);

    // 4) x_dbl = u @ x_proj_w^T (k-split MFMA + reduce) -> dti, Bm
    xproj_mfma_kernel<<<dim3(XKS, MROWS / 64), 256, 0, stream>>>(ub, wbp, xpt);
    xproj_reduce_kernel<<<dim3(MROWS * 32 / 256), 256, 0, stream>>>(xpt, dti, Bm);

    // 5) chunked selective scan; scanC fuses D-skip + silu(z) gate -> ypb (bf16)
    scanA_kernel<<<dim3(D_INNER / 256, NCH, BATCH), 256, 0, stream>>>(
        dti, Bm, dt_w, dt_b, A_param, Pg, Sg);
    scanB_kernel<<<dim3(NREC / 256), 256, 0, stream>>>(Pg, Sg, Hin);
    scanC_kernel<<<dim3(D_INNER / 256, NCH, BATCH), 256, 0, stream>>>(
        dti, Bm, dt_w, dt_b, A_param, Hin, ub, xz, D_param, ypb);

    // 6) out = yp @ out_w^T + out_b   (M=2048, N=1024, K=2048), 256 blocks
    gemm_bf16_kernel<64, true><<<dim3(1024 / 64, MROWS / 128), 256, 0, stream>>>(
        ypb, wbo, out, out_b, MROWS, D_MODEL, D_INNER);
}

// Round 6
// 223.704 us; speedup vs baseline: 2.3785x; 1.0674x over previous
//
#include <hip/hip_runtime.h>
#include <stdint.h>
#include <stddef.h>

#define D_MODEL 1024
#define D_STATE 16
#define D_INNER 2048
#define BATCH   2
#define SEQ     1024
#define MROWS   (BATCH*SEQ)   // 2048

// chunked scan config
#define NCH 32
#define TCH (SEQ/NCH)         // 32
#define NREC (BATCH*D_INNER*D_STATE)  // 65536

// xproj k-split
#define XKS 8
#define XKC (D_INNER/XKS)     // 256

typedef __bf16 bf16x8 __attribute__((ext_vector_type(8)));
typedef float  f32x4  __attribute__((ext_vector_type(4)));

__device__ __forceinline__ unsigned short f2bf(float f) {
    unsigned int u = __float_as_uint(f);
    u += 0x7fffu + ((u >> 16) & 1u);      // RNE
    return (unsigned short)(u >> 16);
}
__device__ __forceinline__ float bf2f(unsigned short v) {
    return __uint_as_float((unsigned int)v << 16);
}

// async global -> LDS, 16B/lane. Global addr is PER-LANE (gather); LDS dest is
// wave-uniform base + lane*16 (m104/m108).
__device__ __forceinline__ void gl_lds16(const unsigned short* g, unsigned short* l) {
    __builtin_amdgcn_global_load_lds(
        (const __attribute__((address_space(1))) unsigned int*)g,
        (__attribute__((address_space(3))) unsigned int*)l, 16, 0, 0);
}

// ---------------- fused fp32 -> bf16 conversions -------------------------------
__global__ void cvt_all_kernel(const float* __restrict__ x,
                               const float* __restrict__ w1,
                               const float* __restrict__ w2,
                               const float* __restrict__ xw,
                               unsigned short* __restrict__ xb,
                               unsigned short* __restrict__ wbi,
                               unsigned short* __restrict__ wbo,
                               unsigned short* __restrict__ wbp) {
    int blk = blockIdx.x, tid = threadIdx.x;
    if (blk < 8192) {
        const float* src; unsigned short* dst; int i;
        if (blk < 2048)      { src = x;  dst = xb;  i = blk * 1024 + tid * 4; }
        else if (blk < 6144) { src = w1; dst = wbi; i = (blk - 2048) * 1024 + tid * 4; }
        else                 { src = w2; dst = wbo; i = (blk - 6144) * 1024 + tid * 4; }
        float4 v = *(const float4*)(src + i);
        ushort4 o;
        o.x = f2bf(v.x); o.y = f2bf(v.y); o.z = f2bf(v.z); o.w = f2bf(v.w);
        *(ushort4*)(dst + i) = o;
    } else {
        int id = (blk - 8192) * 256 + tid;          // 0..65535
        wbp[id] = (id < 17 * D_INNER) ? f2bf(xw[id]) : (unsigned short)0;
    }
}

// ---------------- bf16 MFMA GEMM, BK=64 dual-panel LDS -------------------------
// C[m,n] = sum_k A[m,k]*Bw[n,k]. Tile 128 x NT, 256 thr (4 waves 2x2).
// LDS = two stride-32 panels per operand (k-half-major): each 1KB chunk stages
// 16 rows x 64B of ONE k-half, so ds_read bank pattern matches BK=32.
// Chunk counts per k-iter: A = 128*64*2/1024 = 16; B = NT*64*2/1024 = NT/8.
// (R5 BUG: B used NT/16 -> half the B rows were uninitialized LDS -> NaN.)
// SPLITK2: gridDim.z==2, each z does K/2, C holds partials [z][M][N].
template<int NT, bool SPLITK2, bool OUT_BF16>
__global__ void gemm_bf16_kernel(const unsigned short* __restrict__ A,
                                 const unsigned short* __restrict__ Bw,
                                 void* __restrict__ Cv,
                                 int M, int N, int K) {
    constexpr int NTW = NT / 32;                 // n-frags per wave (4 or 2)
    constexpr int BCH = NT / 8;                  // B chunks per k-iter (16 or 8)
    __shared__ __align__(16) unsigned short Al[2 * 128 * 32];   // 16 KB
    __shared__ __align__(16) unsigned short Bl[2 * NT * 32];

    const int tid  = threadIdx.x;
    const int lane = tid & 63;
    const int wid  = tid >> 6;
    const int wm   = wid >> 1;
    const int wn   = wid & 1;
    const int ln   = lane & 15;
    const int q    = lane >> 4;
    const int mblk = blockIdx.y * 128;
    const int nblk = blockIdx.x * NT;
    const int srow = lane >> 2;                  // 0..15 rows within chunk
    const int spart = lane & 3;                  // 16B part within 64B k-half

    const int kbeg = SPLITK2 ? blockIdx.z * (K / 2) : 0;
    const int kend = SPLITK2 ? kbeg + K / 2 : K;

    f32x4 acc[4][NTW] = {};

    for (int k0 = kbeg; k0 < kend; k0 += 64) {
        // A: 16 chunks (8 rowblks x 2 khalves), 4 per wave
        #pragma unroll
        for (int h = 0; h < 4; ++h) {
            int j = wid * 4 + h;
            int kh = j & 1, rb = j >> 1;
            int row = rb * 16 + srow;
            gl_lds16(A + (size_t)(mblk + row) * K + k0 + kh * 32 + spart * 8,
                     Al + kh * 4096 + rb * 512);
        }
        // B: BCH chunks (NT/16 rowblks x 2 khalves), BCH/4 per wave
        #pragma unroll
        for (int h = 0; h < BCH / 4; ++h) {
            int j = wid * (BCH / 4) + h;
            int kh = j & 1, rb = j >> 1;         // rb in [0, NT/16)
            int row = rb * 16 + srow;            // covers all NT rows
            gl_lds16(Bw + (size_t)(nblk + row) * K + k0 + kh * 32 + spart * 8,
                     Bl + kh * (NT * 32) + rb * 512);
        }
        __syncthreads();

        #pragma unroll
        for (int kh = 0; kh < 2; ++kh) {
            bf16x8 af[4], bfr[NTW];
            #pragma unroll
            for (int mt = 0; mt < 4; ++mt)
                af[mt] = *(const bf16x8*)(Al + kh * 4096 + (wm * 64 + mt * 16 + ln) * 32 + q * 8);
            #pragma unroll
            for (int nt = 0; nt < NTW; ++nt)
                bfr[nt] = *(const bf16x8*)(Bl + kh * (NT * 32) + (wn * (NT/2) + nt * 16 + ln) * 32 + q * 8);
            #pragma unroll
            for (int mt = 0; mt < 4; ++mt)
                #pragma unroll
                for (int nt = 0; nt < NTW; ++nt)
                    acc[mt][nt] = __builtin_amdgcn_mfma_f32_16x16x32_bf16(
                        af[mt], bfr[nt], acc[mt][nt], 0, 0, 0);
        }
        __syncthreads();
    }

    size_t cofs = SPLITK2 ? (size_t)blockIdx.z * M * N : 0;
    #pragma unroll
    for (int mt = 0; mt < 4; ++mt) {
        #pragma unroll
        for (int nt = 0; nt < NTW; ++nt) {
            int col = nblk + wn * (NT/2) + nt * 16 + ln;
            #pragma unroll
            for (int r = 0; r < 4; ++r) {
                int row = mblk + wm * 64 + mt * 16 + q * 4 + r;
                if (OUT_BF16)
                    ((unsigned short*)Cv)[cofs + (size_t)row * N + col] = f2bf(acc[mt][nt][r]);
                else
                    ((float*)Cv)[cofs + (size_t)row * N + col] = acc[mt][nt][r];
            }
        }
    }
}

// gemm2 split-K reduce: out = p0 + p1 + bias
__global__ void splitk_reduce_kernel(const float* __restrict__ part,
                                     const float* __restrict__ bias,
                                     float* __restrict__ out) {
    int i = (blockIdx.x * 256 + threadIdx.x) * 4;   // over 2048*1024
    int n = i & (D_MODEL - 1);
    float4 a = *(const float4*)(part + i);
    float4 b = *(const float4*)(part + (size_t)MROWS * D_MODEL + i);
    float4 bv = *(const float4*)(bias + n);
    float4 o;
    o.x = a.x + b.x + bv.x; o.y = a.y + b.y + bv.y;
    o.z = a.z + b.z + bv.z; o.w = a.w + b.w + bv.w;
    *(float4*)(out + i) = o;
}

// ---------------- causal depthwise conv (k=4) + silu -> bf16 u -----------------
__global__ void conv_silu_kernel(const unsigned short* __restrict__ xzb,
                                 const float* __restrict__ conv_w,
                                 unsigned short* __restrict__ ub) {
    int idx = blockIdx.x * blockDim.x + threadIdx.x;   // m*2048 + d
    int d = idx & (D_INNER - 1);
    int m = idx >> 11;
    int l = m & (SEQ - 1);
    const float* w = conv_w + d * 4;
    float s = 0.f;
    #pragma unroll
    for (int j = 0; j < 4; ++j) {
        if (l - j >= 0) s += w[3 - j] * bf2f(xzb[(size_t)(m - j) * 4096 + d]);
    }
    float sig = 1.f / (1.f + __expf(-s));
    ub[idx] = f2bf(s * sig);
}

// ---------------- xproj mini-GEMM: part[ks][m][n] = ub[m,ks-slice] @ wbp^T -----
__global__ void xproj_mfma_kernel(const unsigned short* __restrict__ ub,
                                  const unsigned short* __restrict__ wbp,
                                  float* __restrict__ part) {
    __shared__ __align__(16) unsigned short Al[64 * 64];  // 8KB
    __shared__ __align__(16) unsigned short Bl[32 * 64];  // 4KB

    const int tid  = threadIdx.x;
    const int lane = tid & 63;
    const int wid  = tid >> 6;
    const int ln   = lane & 15;
    const int q    = lane >> 4;
    const int m0   = blockIdx.y * 64;
    const int ks   = blockIdx.x;
    const int srow = lane >> 3;
    const int spart = lane & 7;

    f32x4 acc[2] = {};

    for (int it = 0; it < 4; ++it) {
        int k0 = ks * XKC + it * 64;
        #pragma unroll
        for (int h = 0; h < 2; ++h) {
            int j = wid * 2 + h;
            int row = j * 8 + srow;
            gl_lds16(ub + (size_t)(m0 + row) * D_INNER + k0 + spart * 8, Al + j * 512);
        }
        {
            int row = wid * 8 + srow;
            gl_lds16(wbp + (size_t)row * D_INNER + k0 + spart * 8, Bl + wid * 512);
        }
        __syncthreads();

        bf16x8 af[2], bfr[2][2];
        #pragma unroll
        for (int kh = 0; kh < 2; ++kh) {
            af[kh] = *(const bf16x8*)(Al + (wid * 16 + ln) * 64 + kh * 32 + q * 8);
            bfr[0][kh] = *(const bf16x8*)(Bl + (0 * 16 + ln) * 64 + kh * 32 + q * 8);
            bfr[1][kh] = *(const bf16x8*)(Bl + (1 * 16 + ln) * 64 + kh * 32 + q * 8);
        }
        #pragma unroll
        for (int kh = 0; kh < 2; ++kh) {
            acc[0] = __builtin_amdgcn_mfma_f32_16x16x32_bf16(af[kh], bfr[0][kh], acc[0], 0, 0, 0);
            acc[1] = __builtin_amdgcn_mfma_f32_16x16x32_bf16(af[kh], bfr[1][kh], acc[1], 0, 0, 0);
        }
        __syncthreads();
    }

    #pragma unroll
    for (int nf = 0; nf < 2; ++nf) {
        #pragma unroll
        for (int r = 0; r < 4; ++r) {
            int m = m0 + wid * 16 + q * 4 + r;
            part[((size_t)ks * MROWS + m) * 32 + nf * 16 + ln] = acc[nf][r];
        }
    }
}

__global__ void xproj_reduce_kernel(const float* __restrict__ part,
                                    float* __restrict__ dti,
                                    float* __restrict__ Bm) {
    int id = blockIdx.x * 256 + threadIdx.x;   // m*32+n
    int m = id >> 5, n = id & 31;
    float s = 0.f;
    #pragma unroll
    for (int ks = 0; ks < XKS; ++ks) s += part[(size_t)ks * MROWS * 32 + id];
    if (n == 0) dti[m] = s;
    else if (n < 17) Bm[(size_t)m * D_STATE + (n - 1)] = s;
}

// ---------------- chunked selective scan ---------------------------------------
__device__ __forceinline__ float softplus_f(float xv) {
    return fmaxf(xv, 0.f) + __logf(1.f + __expf(-fabsf(xv)));
}

__global__ void scanA_kernel(const float* __restrict__ dt_in,
                             const float* __restrict__ Bm,
                             const float* __restrict__ dt_w,
                             const float* __restrict__ dt_b,
                             const float* __restrict__ A_param,
                             float* __restrict__ Pg,
                             float* __restrict__ Sg) {
    __shared__ float sdt[TCH];
    __shared__ float sB[TCH * D_STATE];
    const int tid = threadIdx.x;
    const int b = blockIdx.z, c = blockIdx.y;
    const int d = blockIdx.x * 256 + tid;

    if (tid < TCH) sdt[tid] = dt_in[b * SEQ + c * TCH + tid];
    if (tid < TCH * D_STATE / 4)
        ((float4*)sB)[tid] = ((const float4*)(Bm + ((size_t)(b * SEQ + c * TCH)) * D_STATE))[tid];
    __syncthreads();

    const float dtw = dt_w[d], dtb = dt_b[d];
    float aA[D_STATE], h[D_STATE];
    #pragma unroll
    for (int n4 = 0; n4 < 4; ++n4) {
        float4 ap = ((const float4*)(A_param + (size_t)d * D_STATE))[n4];
        aA[n4*4+0] = -__expf(ap.x); aA[n4*4+1] = -__expf(ap.y);
        aA[n4*4+2] = -__expf(ap.z); aA[n4*4+3] = -__expf(ap.w);
    }
    #pragma unroll
    for (int n = 0; n < D_STATE; ++n) h[n] = 0.f;
    float tsum = 0.f;

    for (int t = 0; t < TCH; ++t) {
        float sp = softplus_f(sdt[t] * dtw + dtb);
        tsum += sp;
        #pragma unroll
        for (int n = 0; n < D_STATE; ++n) {
            float a = __expf(aA[n] * sp);
            h[n] = a * h[n] + sp * sB[t * D_STATE + n];
        }
    }

    size_t base = (size_t)c * NREC + ((size_t)(b * D_INNER + d)) * D_STATE;
    #pragma unroll
    for (int n4 = 0; n4 < 4; ++n4) {
        float4 pv, sv;
        pv.x = __expf(aA[n4*4+0] * tsum); pv.y = __expf(aA[n4*4+1] * tsum);
        pv.z = __expf(aA[n4*4+2] * tsum); pv.w = __expf(aA[n4*4+3] * tsum);
        sv.x = h[n4*4+0]; sv.y = h[n4*4+1]; sv.z = h[n4*4+2]; sv.w = h[n4*4+3];
        *(float4*)(Pg + base + n4 * 4) = pv;
        *(float4*)(Sg + base + n4 * 4) = sv;
    }
}

__global__ void scanB_kernel(const float* __restrict__ Pg,
                             const float* __restrict__ Sg,
                             float* __restrict__ Hin) {
    int idx = blockIdx.x * 256 + threadIdx.x;
    float h = 0.f;
    #pragma unroll
    for (int c = 0; c < NCH; ++c) {
        size_t o = (size_t)c * NREC + idx;
        Hin[o] = h;
        h = Pg[o] * h + Sg[o];
    }
}

// scanC fused with ypost: yp[m,d] = (y + u*D) * silu(z) -> bf16
__global__ void scanC_kernel(const float* __restrict__ dt_in,
                             const float* __restrict__ Bm,
                             const float* __restrict__ dt_w,
                             const float* __restrict__ dt_b,
                             const float* __restrict__ A_param,
                             const float* __restrict__ Hin,
                             const unsigned short* __restrict__ ub,
                             const unsigned short* __restrict__ xzb,
                             const float* __restrict__ Dp,
                             unsigned short* __restrict__ ypb) {
    __shared__ float sdt[TCH];
    __shared__ float sB[TCH * D_STATE];
    const int tid = threadIdx.x;
    const int b = blockIdx.z, c = blockIdx.y;
    const int d = blockIdx.x * 256 + tid;

    if (tid < TCH) sdt[tid] = dt_in[b * SEQ + c * TCH + tid];
    if (tid < TCH * D_STATE / 4)
        ((float4*)sB)[tid] = ((const float4*)(Bm + ((size_t)(b * SEQ + c * TCH)) * D_STATE))[tid];
    __syncthreads();

    const float dtw = dt_w[d], dtb = dt_b[d];
    const float Dv = Dp[d];
    float aA[D_STATE], h[D_STATE];
    #pragma unroll
    for (int n4 = 0; n4 < 4; ++n4) {
        float4 ap = ((const float4*)(A_param + (size_t)d * D_STATE))[n4];
        aA[n4*4+0] = -__expf(ap.x); aA[n4*4+1] = -__expf(ap.y);
        aA[n4*4+2] = -__expf(ap.z); aA[n4*4+3] = -__expf(ap.w);
    }
    size_t hbase = (size_t)c * NREC + ((size_t)(b * D_INNER + d)) * D_STATE;
    #pragma unroll
    for (int n4 = 0; n4 < 4; ++n4) {
        float4 hv = *(const float4*)(Hin + hbase + n4 * 4);
        h[n4*4+0] = hv.x; h[n4*4+1] = hv.y; h[n4*4+2] = hv.z; h[n4*4+3] = hv.w;
    }

    const size_t mrow0 = (size_t)b * SEQ + c * TCH;
    for (int t = 0; t < TCH; ++t) {
        float sp = softplus_f(sdt[t] * dtw + dtb);
        float y0 = 0.f, y1 = 0.f, y2 = 0.f, y3 = 0.f;
        #pragma unroll
        for (int n4 = 0; n4 < 4; ++n4) {
            #pragma unroll
            for (int j = 0; j < 4; ++j) {
                int n = n4 * 4 + j;
                float Bv = sB[t * D_STATE + n];
                float a = __expf(aA[n] * sp);
                h[n] = a * h[n] + sp * Bv;
                float p = h[n] * Bv;
                if (n4 == 0) y0 += p; else if (n4 == 1) y1 += p;
                else if (n4 == 2) y2 += p; else y3 += p;
            }
        }
        float y = (y0 + y1) + (y2 + y3);
        size_t m = mrow0 + t;
        float z  = bf2f(xzb[m * 4096 + D_INNER + d]);
        float sz = z / (1.f + __expf(-z));
        float uv = bf2f(ub[m * D_INNER + d]);
        ypb[m * D_INNER + d] = f2bf((y + uv * Dv) * sz);
    }
}

// ---------------- launch -------------------------------------------------------
extern "C" void kernel_launch(void* const* d_in, const int* in_sizes, int n_in,
                              void* d_out, int out_size, void* d_ws, size_t ws_size,
                              hipStream_t stream) {
    const float* x         = (const float*)d_in[0];
    const float* in_proj_w = (const float*)d_in[1];
    const float* conv_w    = (const float*)d_in[2];
    const float* x_proj_w  = (const float*)d_in[3];
    const float* dt_w      = (const float*)d_in[4];
    const float* dt_b      = (const float*)d_in[5];
    const float* A_param   = (const float*)d_in[6];
    const float* D_param   = (const float*)d_in[7];
    const float* out_w     = (const float*)d_in[8];
    const float* out_b     = (const float*)d_in[9];
    float* out = (float*)d_out;

    // workspace layout — all regions disjoint (92 MB)
    char* ws = (char*)d_ws;
    unsigned short* xb  = (unsigned short*)(ws);                      //  4 MB
    unsigned short* wbi = (unsigned short*)(ws + (4u  << 20));        //  8 MB
    unsigned short* wbo = (unsigned short*)(ws + (12u << 20));        //  4 MB
    unsigned short* xzb = (unsigned short*)(ws + (16u << 20));        // 16 MB (bf16)
    unsigned short* ub  = (unsigned short*)(ws + (32u << 20));        //  8 MB
    float*          dti = (float*)(ws + (40u << 20));                 //  8 KB
    float*          Bm  = (float*)(ws + (40u << 20) + (64u  << 10));  // 128 KB
    unsigned short* wbp = (unsigned short*)(ws + (40u << 20) + (192u << 10)); // 128 KB
    float*          xpt = (float*)(ws + (40u << 20) + (512u << 10));  //  2 MB
    float*          Pg  = (float*)(ws + (44u << 20));                 //  8 MB
    float*          Sg  = (float*)(ws + (52u << 20));                 //  8 MB
    float*          Hin = (float*)(ws + (60u << 20));                 //  8 MB
    unsigned short* ypb = (unsigned short*)(ws + (68u << 20));        //  8 MB
    float*          g2p = (float*)(ws + (76u << 20));                 // 16 MB partials

    // 1) fp32 -> bf16 conversions
    cvt_all_kernel<<<dim3(8448), 256, 0, stream>>>(
        x, in_proj_w, out_w, x_proj_w, xb, wbi, wbo, wbp);

    // 2) xz = x @ in_proj_w^T -> bf16 (M=2048, N=4096, K=1024), 512 blocks
    gemm_bf16_kernel<128, false, true><<<dim3(4096 / 128, MROWS / 128), 256, 0, stream>>>(
        xb, wbi, xzb, MROWS, 2 * D_INNER, D_MODEL);

    // 3) u = silu(causal_conv(xz[:, :2048])) -> bf16
    conv_silu_kernel<<<dim3(MROWS * D_INNER / 256), 256, 0, stream>>>(xzb, conv_w, ub);

    // 4) x_dbl = u @ x_proj_w^T (k-split MFMA + reduce) -> dti, Bm
    xproj_mfma_kernel<<<dim3(XKS, MROWS / 64), 256, 0, stream>>>(ub, wbp, xpt);
    xproj_reduce_kernel<<<dim3(MROWS * 32 / 256), 256, 0, stream>>>(xpt, dti, Bm);

    // 5) chunked selective scan; scanC fuses D-skip + silu(z) gate -> ypb (bf16)
    scanA_kernel<<<dim3(D_INNER / 256, NCH, BATCH), 256, 0, stream>>>(
        dti, Bm, dt_w, dt_b, A_param, Pg, Sg);
    scanB_kernel<<<dim3(NREC / 256), 256, 0, stream>>>(Pg, Sg, Hin);
    scanC_kernel<<<dim3(D_INNER / 256, NCH, BATCH), 256, 0, stream>>>(
        dti, Bm, dt_w, dt_b, A_param, Hin, ub, xzb, D_param, ypb);

    // 6) out partials = yp @ out_w^T (M=2048, N=1024, K=2048 split 2), 512 blocks
    gemm_bf16_kernel<64, true, false><<<dim3(1024 / 64, MROWS / 128, 2), 256, 0, stream>>>(
        ypb, wbo, g2p, MROWS, D_MODEL, D_INNER);

    // 7) out = p0 + p1 + out_b
    splitk_reduce_kernel<<<dim3(MROWS * D_MODEL / 1024), 256, 0, stream>>>(g2p, out_b, out);
}